// Round 2
// baseline (146.696 us; speedup 1.0000x reference)
//
#include <hip/hip_runtime.h>

// Caps_BN: BatchNorm2d (affine=False, training stats) + grouped 1x1 conv (16 groups
// of 32x32) + bias, folded: out = (W * rstd) @ x + (bias - (W*rstd) @ mean).
//
// Shapes: x (64, 512, 32, 32) f32; weight (16, 32, 32) f32; bias (512,) f32.
// N*H*W per channel = 64*1024 = 65536.
//
// Workspace layout (floats):
//   [0, 512)          mean per channel
//   [512, 1024)       rstd per channel
//   [1024, 17408)     W' folded weight (c, o, i)
//   [17408, 17920)    b' folded bias (c, o)

#define NELEM_PER_CH 65536.0f

__global__ __launch_bounds__(256) void caps_stats(const float* __restrict__ x,
                                                  float* __restrict__ ws) {
    const int ch = blockIdx.x;      // 0..511
    const int tid = threadIdx.x;    // 0..255
    const float4* __restrict__ x4 = (const float4*)x;

    float s = 0.f, ss = 0.f;
    // channel row of image n: 1024 floats = 256 float4 at x4[(n*512 + ch)*256 + q]
#pragma unroll 4
    for (int n = 0; n < 64; ++n) {
        float4 v = x4[((size_t)n * 512 + ch) * 256 + tid];
        s  += v.x + v.y + v.z + v.w;
        ss += v.x * v.x + v.y * v.y + v.z * v.z + v.w * v.w;
    }

    // wave64 reduce
#pragma unroll
    for (int off = 32; off > 0; off >>= 1) {
        s  += __shfl_down(s, off);
        ss += __shfl_down(ss, off);
    }
    __shared__ float red[4][2];
    const int wid = tid >> 6;
    if ((tid & 63) == 0) { red[wid][0] = s; red[wid][1] = ss; }
    __syncthreads();
    if (tid == 0) {
        float S = 0.f, SS = 0.f;
#pragma unroll
        for (int w = 0; w < 4; ++w) { S += red[w][0]; SS += red[w][1]; }
        float mean = S / NELEM_PER_CH;
        float var = SS / NELEM_PER_CH - mean * mean;
        ws[ch] = mean;
        ws[512 + ch] = rsqrtf(var + 1e-5f);
    }
}

// One block per capsule c; 1024 threads, thread t = o*32 + i.
__global__ __launch_bounds__(1024) void caps_fold(const float* __restrict__ w,
                                                  const float* __restrict__ bias,
                                                  float* __restrict__ ws) {
    const int c = blockIdx.x;
    const int t = threadIdx.x;
    const int o = t >> 5;
    const int i = t & 31;

    const float mean = ws[c * 32 + i];
    const float rstd = ws[512 + c * 32 + i];
    const float wv = w[c * 1024 + t] * rstd;
    ws[1024 + c * 1024 + t] = wv;

    // reduce wv*mean over i within each aligned 32-lane half of the wave
    float prod = wv * mean;
#pragma unroll
    for (int off = 16; off > 0; off >>= 1) prod += __shfl_xor(prod, off);
    if (i == 0) ws[17408 + c * 32 + o] = bias[c * 32 + o] - prod;
}

// Main: one thread per 4 consecutive hw positions (one float4 column group).
// grid (16, 64) = (c, n); block 256 (covers all 1024 hw of the (n,c) tile).
__global__ __launch_bounds__(256) void caps_main(const float* __restrict__ x,
                                                 const float* __restrict__ ws,
                                                 float* __restrict__ out) {
    const int c = blockIdx.x;
    const int n = blockIdx.y;
    const int t = threadIdx.x;                       // hw4 index 0..255

    const float4* __restrict__ x4 = (const float4*)x;
    float4* __restrict__ o4 = (float4*)out;
    // float4 index of (n, c, i=0, hw=4t)
    const size_t base4 = (((size_t)n * 16 + c) * 32) * 256 + t;

    const float* __restrict__ Wc = ws + 1024 + c * 1024;   // W'[c][o][i], block-uniform
    const float* __restrict__ b2 = ws + 17408 + c * 32;    // b'[c][o]

    float4 xv[32];
#pragma unroll
    for (int i = 0; i < 32; ++i) xv[i] = x4[base4 + (size_t)i * 256];

#pragma unroll 4
    for (int o = 0; o < 32; ++o) {
        const float b = b2[o];                       // uniform scalar load
        float4 acc;
        acc.x = b; acc.y = b; acc.z = b; acc.w = b;
#pragma unroll
        for (int i = 0; i < 32; ++i) {
            const float wv = Wc[o * 32 + i];         // uniform -> s_load row
            acc.x += wv * xv[i].x;
            acc.y += wv * xv[i].y;
            acc.z += wv * xv[i].z;
            acc.w += wv * xv[i].w;
        }
        o4[base4 + (size_t)o * 256] = acc;
    }
}

extern "C" void kernel_launch(void* const* d_in, const int* in_sizes, int n_in,
                              void* d_out, int out_size, void* d_ws, size_t ws_size,
                              hipStream_t stream) {
    const float* x    = (const float*)d_in[0];
    const float* w    = (const float*)d_in[1];
    const float* bias = (const float*)d_in[2];
    float* out = (float*)d_out;
    float* ws  = (float*)d_ws;

    caps_stats<<<512, 256, 0, stream>>>(x, ws);
    caps_fold<<<16, 1024, 0, stream>>>(w, bias, ws);
    caps_main<<<dim3(16, 64), 256, 0, stream>>>(x, ws, out);
}

// Round 3
// 143.598 us; speedup vs baseline: 1.0216x; 1.0216x over previous
//
#include <hip/hip_runtime.h>

// Caps_BN: BatchNorm2d (affine=False, training stats) + grouped 1x1 conv (16 groups
// of 32x32) + bias, folded: out = (W * rstd) @ x + (bias - (W*rstd) @ mean).
//
// Shapes: x (64, 512, 32, 32) f32; weight (16, 32, 32) f32; bias (512,) f32.
//
// Workspace layout (floats):
//   [0, 512)          mean per channel
//   [512, 1024)       rstd per channel
//   [1024, 17408)     WT folded weight, TRANSPOSED: WT[c][i][o]
//   [17408, 17920)    b' folded bias (c, o)

#define NELEM_PER_CH 65536.0f

__global__ __launch_bounds__(256) void caps_stats(const float* __restrict__ x,
                                                  float* __restrict__ ws) {
    const int ch = blockIdx.x;      // 0..511
    const int tid = threadIdx.x;    // 0..255
    const float4* __restrict__ x4 = (const float4*)x;

    float s = 0.f, ss = 0.f;
#pragma unroll 4
    for (int n = 0; n < 64; ++n) {
        float4 v = x4[((size_t)n * 512 + ch) * 256 + tid];
        s  += v.x + v.y + v.z + v.w;
        ss += v.x * v.x + v.y * v.y + v.z * v.z + v.w * v.w;
    }

#pragma unroll
    for (int off = 32; off > 0; off >>= 1) {
        s  += __shfl_down(s, off);
        ss += __shfl_down(ss, off);
    }
    __shared__ float red[4][2];
    const int wid = tid >> 6;
    if ((tid & 63) == 0) { red[wid][0] = s; red[wid][1] = ss; }
    __syncthreads();
    if (tid == 0) {
        float S = 0.f, SS = 0.f;
#pragma unroll
        for (int w = 0; w < 4; ++w) { S += red[w][0]; SS += red[w][1]; }
        float mean = S / NELEM_PER_CH;
        float var = SS / NELEM_PER_CH - mean * mean;
        ws[ch] = mean;
        ws[512 + ch] = rsqrtf(var + 1e-5f);
    }
}

// One block per capsule c; 1024 threads, thread t = o*32 + i. Stores W' TRANSPOSED.
__global__ __launch_bounds__(1024) void caps_fold(const float* __restrict__ w,
                                                  const float* __restrict__ bias,
                                                  float* __restrict__ ws) {
    const int c = blockIdx.x;
    const int t = threadIdx.x;
    const int o = t >> 5;
    const int i = t & 31;

    const float mean = ws[c * 32 + i];
    const float rstd = ws[512 + c * 32 + i];
    const float wv = w[c * 1024 + t] * rstd;
    ws[1024 + c * 1024 + i * 32 + o] = wv;   // WT[c][i][o]

    float prod = wv * mean;
#pragma unroll
    for (int off = 16; off > 0; off >>= 1) prod += __shfl_xor(prod, off);
    if (i == 0) ws[17408 + c * 32 + o] = bias[c * 32 + o] - prod;
}

// Main: accumulator-major. One thread owns 2 consecutive hw positions (float2),
// holds acc[32] (64 VGPR), streams x_i one float2 at a time.
// grid (2, 16, 64) = (hw2/256, c, n); block 256.
__global__ __launch_bounds__(256) void caps_main(const float* __restrict__ x,
                                                 const float* __restrict__ ws,
                                                 float* __restrict__ out) {
    const int c = blockIdx.y;
    const int n = blockIdx.z;
    const int hw2 = blockIdx.x * 256 + threadIdx.x;   // 0..511, float2 column index

    const float2* __restrict__ x2 = (const float2*)x;
    float2* __restrict__ o2 = (float2*)out;
    const size_t base2 = (((size_t)n * 16 + c) * 32) * 512 + hw2;

    const float* __restrict__ WT = ws + 1024 + c * 1024;  // WT[i][o], block-uniform
    const float* __restrict__ bp = ws + 17408 + c * 32;   // b'[o]

    float2 acc[32];
#pragma unroll
    for (int o = 0; o < 32; ++o) {
        const float b = bp[o];
        acc[o].x = b; acc[o].y = b;
    }

#pragma unroll 4
    for (int i = 0; i < 32; ++i) {
        const float2 xv = x2[base2 + (size_t)i * 512];
        const float* __restrict__ wt = WT + i * 32;       // 32 contiguous -> s_load
#pragma unroll
        for (int o = 0; o < 32; ++o) {
            acc[o].x += wt[o] * xv.x;                     // v_fmac v, s, v
            acc[o].y += wt[o] * xv.y;
        }
    }

#pragma unroll 4
    for (int o = 0; o < 32; ++o)
        o2[base2 + (size_t)o * 512] = acc[o];
}

extern "C" void kernel_launch(void* const* d_in, const int* in_sizes, int n_in,
                              void* d_out, int out_size, void* d_ws, size_t ws_size,
                              hipStream_t stream) {
    const float* x    = (const float*)d_in[0];
    const float* w    = (const float*)d_in[1];
    const float* bias = (const float*)d_in[2];
    float* out = (float*)d_out;
    float* ws  = (float*)d_ws;

    caps_stats<<<512, 256, 0, stream>>>(x, ws);
    caps_fold<<<16, 1024, 0, stream>>>(w, bias, ws);
    caps_main<<<dim3(2, 16, 64), 256, 0, stream>>>(x, ws, out);
}

// Round 4
// 125.271 us; speedup vs baseline: 1.1710x; 1.1463x over previous
//
#include <hip/hip_runtime.h>

// Caps_BN: BatchNorm2d (affine=False, training stats) + grouped 1x1 conv (16 groups
// of 32x32) + bias, folded: out = (W * rstd) @ x + (bias - (W*rstd) @ mean).
//
// Shapes: x (64, 512, 32, 32) f32; weight (16, 32, 32) f32; bias (512,) f32.
//
// Workspace layout (floats):
//   [0, 512)          mean per channel
//   [512, 1024)       rstd per channel
//   [1024, 17408)     WT folded weight, TRANSPOSED: WT[c][i][o]
//   [17408, 17920)    b' folded bias (c, o)
//
// Memory strategy (R3 post-mortem):
//  - stores: scalar 4B/lane (256B/wave) — the only pattern measured at exactly
//    1.0x WRITE_SIZE (R1); float2/float4 store shapes measured 2.9x/1.5x.
//  - out stores are NONTEMPORAL so they don't allocate in L3: x (134 MB) fits in
//    the 256 MB L3 after caps_stats streams it; keeping out from evicting x lets
//    caps_main read x at L3 bandwidth (R1 evidence: 50% of x was L3-served even
//    without nt; the other 50% was evicted by out allocations).

#define NELEM_PER_CH 65536.0f

__global__ __launch_bounds__(256) void caps_stats(const float* __restrict__ x,
                                                  float* __restrict__ ws) {
    const int ch = blockIdx.x;      // 0..511
    const int tid = threadIdx.x;    // 0..255
    const float4* __restrict__ x4 = (const float4*)x;

    float s = 0.f, ss = 0.f;
#pragma unroll 4
    for (int n = 0; n < 64; ++n) {
        float4 v = x4[((size_t)n * 512 + ch) * 256 + tid];
        s  += v.x + v.y + v.z + v.w;
        ss += v.x * v.x + v.y * v.y + v.z * v.z + v.w * v.w;
    }

#pragma unroll
    for (int off = 32; off > 0; off >>= 1) {
        s  += __shfl_down(s, off);
        ss += __shfl_down(ss, off);
    }
    __shared__ float red[4][2];
    const int wid = tid >> 6;
    if ((tid & 63) == 0) { red[wid][0] = s; red[wid][1] = ss; }
    __syncthreads();
    if (tid == 0) {
        float S = 0.f, SS = 0.f;
#pragma unroll
        for (int w = 0; w < 4; ++w) { S += red[w][0]; SS += red[w][1]; }
        float mean = S / NELEM_PER_CH;
        float var = SS / NELEM_PER_CH - mean * mean;
        ws[ch] = mean;
        ws[512 + ch] = rsqrtf(var + 1e-5f);
    }
}

// One block per capsule c; 1024 threads, thread t = o*32 + i. Stores W' TRANSPOSED.
__global__ __launch_bounds__(1024) void caps_fold(const float* __restrict__ w,
                                                  const float* __restrict__ bias,
                                                  float* __restrict__ ws) {
    const int c = blockIdx.x;
    const int t = threadIdx.x;
    const int o = t >> 5;
    const int i = t & 31;

    const float mean = ws[c * 32 + i];
    const float rstd = ws[512 + c * 32 + i];
    const float wv = w[c * 1024 + t] * rstd;
    ws[1024 + c * 1024 + i * 32 + o] = wv;   // WT[c][i][o]

    float prod = wv * mean;
#pragma unroll
    for (int off = 16; off > 0; off >>= 1) prod += __shfl_xor(prod, off);
    if (i == 0) ws[17408 + c * 32 + o] = bias[c * 32 + o] - prod;
}

// Main: accumulator-major, 2 scalar hw columns per thread (hw = B + t, B + t + 512).
// grid (2, 16, 64) = (hw-half, c, n); block 256. All global access 4B/lane.
__global__ __launch_bounds__(256, 6) void caps_main(const float* __restrict__ x,
                                                    const float* __restrict__ ws,
                                                    float* __restrict__ out) {
    const int c = blockIdx.y;
    const int n = blockIdx.z;
    const int t = threadIdx.x;                         // 0..255
    const int hw0 = blockIdx.x * 256 + t;              // col A: 0..511

    const size_t tile = (((size_t)n * 16 + c) * 32) * 1024;
    const float* __restrict__ xa = x + tile + hw0;         // col A, i-stride 1024
    const float* __restrict__ xb = xa + 512;               // col B
    float* __restrict__ oa = out + tile + hw0;
    float* __restrict__ ob = oa + 512;

    const float* __restrict__ WT = ws + 1024 + c * 1024;   // WT[i][o], block-uniform
    const float* __restrict__ bp = ws + 17408 + c * 32;    // b'[o]

    float acc0[32], acc1[32];
#pragma unroll
    for (int o = 0; o < 32; ++o) {
        const float b = bp[o];
        acc0[o] = b; acc1[o] = b;
    }

#pragma unroll 2
    for (int i = 0; i < 32; ++i) {
        const float va = xa[(size_t)i * 1024];
        const float vb = xb[(size_t)i * 1024];
        const float* __restrict__ wt = WT + i * 32;        // 32 contiguous -> s_load x16
#pragma unroll
        for (int o = 0; o < 32; ++o) {
            acc0[o] += wt[o] * va;                         // v_fmac v, s, v
            acc1[o] += wt[o] * vb;
        }
    }

#pragma unroll 4
    for (int o = 0; o < 32; ++o) {
        __builtin_nontemporal_store(acc0[o], oa + (size_t)o * 1024);
        __builtin_nontemporal_store(acc1[o], ob + (size_t)o * 1024);
    }
}

extern "C" void kernel_launch(void* const* d_in, const int* in_sizes, int n_in,
                              void* d_out, int out_size, void* d_ws, size_t ws_size,
                              hipStream_t stream) {
    const float* x    = (const float*)d_in[0];
    const float* w    = (const float*)d_in[1];
    const float* bias = (const float*)d_in[2];
    float* out = (float*)d_out;
    float* ws  = (float*)d_ws;

    caps_stats<<<512, 256, 0, stream>>>(x, ws);
    caps_fold<<<16, 1024, 0, stream>>>(w, bias, ws);
    caps_main<<<dim3(2, 16, 64), 256, 0, stream>>>(x, ws, out);
}

// Round 5
// 74.834 us; speedup vs baseline: 1.9603x; 1.6740x over previous
//
#include <hip/hip_runtime.h>

// Caps_BN: BatchNorm2d (affine=False, training stats) + grouped 1x1 conv (16 groups
// of 32x32) + bias, folded: out = (W * rstd) @ x + (bias - (W*rstd) @ mean).
//
// Shapes: x (64, 512, 32, 32) f32; weight (16, 32, 32) f32; bias (512,) f32.
//
// Workspace layout (floats):
//   [0, 512)          mean per channel
//   [512, 1024)       rstd per channel
//   [1024, 17408)     W' folded weight (c, o, i)   [row layout, like R1]
//   [17408, 17920)    b' folded bias (c, o)
//
// Lessons encoded here:
//  - R2/R3/R4: any per-thread accumulator array >~32 floats spills to scratch
//    (VGPR_Count 40-44 vs 64+ live floats = spill signature), inflating
//    WRITE_SIZE to 1.5-2.9x and flushing x out of L3 (FETCH back to 128 MB).
//    Only R1's shape (xv[32] in regs, ONE streamed acc per o) measured clean:
//    VGPR 52, WRITE exactly 131072 KB.
//  - R1's limiter: 32-deep dependent FMA chain per o = 50% VALUBusy. Fixed here
//    with 4 independent partial sums (no extra x registers).

#define NELEM_PER_CH 65536.0f

__global__ __launch_bounds__(256) void caps_stats(const float* __restrict__ x,
                                                  float* __restrict__ ws) {
    const int ch = blockIdx.x;      // 0..511
    const int tid = threadIdx.x;    // 0..255
    const float4* __restrict__ x4 = (const float4*)x;

    float s = 0.f, ss = 0.f;
#pragma unroll 4
    for (int n = 0; n < 64; ++n) {
        float4 v = x4[((size_t)n * 512 + ch) * 256 + tid];
        s  += v.x + v.y + v.z + v.w;
        ss += v.x * v.x + v.y * v.y + v.z * v.z + v.w * v.w;
    }

#pragma unroll
    for (int off = 32; off > 0; off >>= 1) {
        s  += __shfl_down(s, off);
        ss += __shfl_down(ss, off);
    }
    __shared__ float red[4][2];
    const int wid = tid >> 6;
    if ((tid & 63) == 0) { red[wid][0] = s; red[wid][1] = ss; }
    __syncthreads();
    if (tid == 0) {
        float S = 0.f, SS = 0.f;
#pragma unroll
        for (int w = 0; w < 4; ++w) { S += red[w][0]; SS += red[w][1]; }
        float mean = S / NELEM_PER_CH;
        float var = SS / NELEM_PER_CH - mean * mean;
        ws[ch] = mean;
        ws[512 + ch] = rsqrtf(var + 1e-5f);
    }
}

// One block per capsule c; 1024 threads, thread t = o*32 + i. Row layout W'[c][o][i].
__global__ __launch_bounds__(1024) void caps_fold(const float* __restrict__ w,
                                                  const float* __restrict__ bias,
                                                  float* __restrict__ ws) {
    const int c = blockIdx.x;
    const int t = threadIdx.x;
    const int o = t >> 5;
    const int i = t & 31;

    const float mean = ws[c * 32 + i];
    const float rstd = ws[512 + c * 32 + i];
    const float wv = w[c * 1024 + t] * rstd;
    ws[1024 + c * 1024 + t] = wv;            // W'[c][o][i]

    float prod = wv * mean;
#pragma unroll
    for (int off = 16; off > 0; off >>= 1) prod += __shfl_xor(prod, off);
    if (i == 0) ws[17408 + c * 32 + o] = bias[c * 32 + o] - prod;
}

// Main: R1 structure. One thread per hw column; xv[32] in regs; per-o streamed
// accumulator, but split into 4 independent partials (chain 32 -> 8).
// grid (4, 16, 64) = (hw/256, c, n); block 256.
__global__ __launch_bounds__(256) void caps_main(const float* __restrict__ x,
                                                 const float* __restrict__ ws,
                                                 float* __restrict__ out) {
    const int hw = blockIdx.x * 256 + threadIdx.x;  // 0..1023
    const int c = blockIdx.y;
    const int n = blockIdx.z;

    const size_t base = (((size_t)n * 16 + c) * 32) * 1024 + hw;
    const float* __restrict__ Wc = ws + 1024 + c * 1024;   // W'[c][o][i], block-uniform
    const float* __restrict__ b2 = ws + 17408 + c * 32;    // b'[c][o]

    float xv[32];
#pragma unroll
    for (int i = 0; i < 32; ++i) xv[i] = x[base + (size_t)i * 1024];

#pragma unroll 4
    for (int o = 0; o < 32; ++o) {
        const float* __restrict__ wr = Wc + o * 32;        // contiguous -> s_load rows
        float p0 = 0.f, p1 = 0.f, p2 = 0.f, p3 = 0.f;
#pragma unroll
        for (int i = 0; i < 32; i += 4) {
            p0 += wr[i + 0] * xv[i + 0];
            p1 += wr[i + 1] * xv[i + 1];
            p2 += wr[i + 2] * xv[i + 2];
            p3 += wr[i + 3] * xv[i + 3];
        }
        const float r = b2[o] + ((p0 + p1) + (p2 + p3));
        // nt store: out is never re-read; keep it from evicting L3-resident x.
        __builtin_nontemporal_store(r, out + base + (size_t)o * 1024);
    }
}

extern "C" void kernel_launch(void* const* d_in, const int* in_sizes, int n_in,
                              void* d_out, int out_size, void* d_ws, size_t ws_size,
                              hipStream_t stream) {
    const float* x    = (const float*)d_in[0];
    const float* w    = (const float*)d_in[1];
    const float* bias = (const float*)d_in[2];
    float* out = (float*)d_out;
    float* ws  = (float*)d_ws;

    caps_stats<<<512, 256, 0, stream>>>(x, ws);
    caps_fold<<<16, 1024, 0, stream>>>(w, bias, ws);
    caps_main<<<dim3(4, 16, 64), 256, 0, stream>>>(x, ws, out);
}